// Round 10
// baseline (171.968 us; speedup 1.0000x reference)
//
#include <hip/hip_runtime.h>

// GATv2, 2 layers, F=64, H=2.
// Edge list (np.unique) is sorted by (src,dst), symmetric; self-loops are the
// last N entries. in-neighbors(v) = dst[src-run of v] + self loop.
//
// fs16/fd16 fp16, per-node CHUNK layout: 16 chunks x 16B, chunk c =
//   (h0 f[4c..4c+3] | h1 f[4c..4c+3]) -> one dwordx4 per edge per lane.
// gat: persistent strided waves (node-level pipeline) x [16 f-lanes x 4
//      edge-slots]; packed fp16 + dot2 logits; 4-DPP reduce; depth-3 gather
//      pipeline; self-edge in slot 0.

#define RLN2 1.4426950408889634f

typedef _Float16 half8v __attribute__((ext_vector_type(8)));
typedef _Float16 half2v __attribute__((ext_vector_type(2)));

template <int CTRL>
__device__ __forceinline__ float dpp_add(float x) {
  return x + __int_as_float(__builtin_amdgcn_update_dpp(
                 0, __float_as_int(x), CTRL, 0xF, 0xF, true));
}

__device__ __forceinline__ float xor16_add(float x) {
  return x + __int_as_float(
                 __builtin_amdgcn_ds_swizzle(__float_as_int(x), 0x401F));
}

__device__ __forceinline__ float dot2(half2v a, half2v b, float c) {
#if __has_builtin(__builtin_amdgcn_fdot2)
  return __builtin_amdgcn_fdot2(a, b, c, false);
#else
  return fmaf((float)a.x, (float)b.x, fmaf((float)a.y, (float)b.y, c));
#endif
}

// row_start[v] = lower_bound(src[0..EM), v); row_start[n] = EM.
__global__ void rowstart_kernel(const int* __restrict__ src,
                                int* __restrict__ row_start, int EM, int n) {
  int v = blockIdx.x * blockDim.x + threadIdx.x;
  if (v > n) return;
  if (v == n) { row_start[n] = EM; return; }
  int lo = 0, hi = EM;
  while (lo < hi) {
    int mid = (lo + hi) >> 1;
    if (src[mid] < v) lo = mid + 1; else hi = mid;
  }
  row_start[v] = lo;
}

// Fused projection: block = (64-row tile) x (32-col half).
// LDS: WsL[4096] | WdL[4096] packed quads, hL[64][68] padded.
// 512 threads: jh = tid&15, rg = tid>>4 (2 rows each).
// Outputs fp16 chunk layout: buf[n*128 + (f>>2)*8 + head*4 + (f&3)].
__global__ __launch_bounds__(512) void proj2_kernel(
    const float* __restrict__ hin, const float* __restrict__ Ws,
    const float* __restrict__ bs, const float* __restrict__ Wd,
    const float* __restrict__ bd, _Float16* __restrict__ fs16,
    _Float16* __restrict__ fd16, int n) {
  __shared__ float lds[12544];
  int tid = threadIdx.x;
  int tile = blockIdx.x >> 1;
  int half = blockIdx.x & 1;
  int fb = half * 32;
  int row0 = tile * 64;

  const float4* Ws4 = (const float4*)Ws;
  const float4* Wd4 = (const float4*)Wd;
#pragma unroll
  for (int t = 0; t < 2; ++t) {
    int g = tid + t * 512;
    int k = g >> 4, part = (g >> 3) & 1, c4 = g & 7;
    int srcf4 = k * 32 + part * 16 + half * 8 + c4;
    float4 vs = Ws4[srcf4];
    float4 vd = Wd4[srcf4];
    int base = k * 64 + 8 * c4 + part;
    lds[base + 0] = vs.x; lds[base + 2] = vs.y;
    lds[base + 4] = vs.z; lds[base + 6] = vs.w;
    lds[4096 + base + 0] = vd.x; lds[4096 + base + 2] = vd.y;
    lds[4096 + base + 4] = vd.z; lds[4096 + base + 6] = vd.w;
  }
  const float4* h4 = (const float4*)hin;
#pragma unroll
  for (int t = 0; t < 2; ++t) {
    int idx = tid + t * 512;
    int r = idx >> 4, c = idx & 15;
    int rr = min(row0 + r, n - 1);
    *(float4*)&lds[8192 + r * 68 + c * 4] = h4[(size_t)rr * 16 + c];
  }
  __syncthreads();

  const float* WsL = lds;
  const float* WdL = lds + 4096;
  const float* hL = lds + 8192;

  int jh = tid & 15;
  int rg = tid >> 4;
  int r0 = rg * 2;

  float4 as0 = make_float4(0, 0, 0, 0), as1 = make_float4(0, 0, 0, 0);
  float4 ad0 = make_float4(0, 0, 0, 0), ad1 = make_float4(0, 0, 0, 0);

#pragma unroll 4
  for (int k4 = 0; k4 < 16; ++k4) {
    float4 hv0 = *(const float4*)&hL[r0 * 68 + k4 * 4];
    float4 hv1 = *(const float4*)&hL[(r0 + 1) * 68 + k4 * 4];
    float h0a[4] = {hv0.x, hv0.y, hv0.z, hv0.w};
    float h1a[4] = {hv1.x, hv1.y, hv1.z, hv1.w};
#pragma unroll
    for (int kk = 0; kk < 4; ++kk) {
      int k = k4 * 4 + kk;
      float4 ws = *(const float4*)&WsL[k * 64 + jh * 4];
      float4 wd = *(const float4*)&WdL[k * 64 + jh * 4];
      as0.x = fmaf(h0a[kk], ws.x, as0.x); as0.y = fmaf(h0a[kk], ws.y, as0.y);
      as0.z = fmaf(h0a[kk], ws.z, as0.z); as0.w = fmaf(h0a[kk], ws.w, as0.w);
      as1.x = fmaf(h1a[kk], ws.x, as1.x); as1.y = fmaf(h1a[kk], ws.y, as1.y);
      as1.z = fmaf(h1a[kk], ws.z, as1.z); as1.w = fmaf(h1a[kk], ws.w, as1.w);
      ad0.x = fmaf(h0a[kk], wd.x, ad0.x); ad0.y = fmaf(h0a[kk], wd.y, ad0.y);
      ad0.z = fmaf(h0a[kk], wd.z, ad0.z); ad0.w = fmaf(h0a[kk], wd.w, ad0.w);
      ad1.x = fmaf(h1a[kk], wd.x, ad1.x); ad1.y = fmaf(h1a[kk], wd.y, ad1.y);
      ad1.z = fmaf(h1a[kk], wd.z, ad1.z); ad1.w = fmaf(h1a[kk], wd.w, ad1.w);
    }
  }

  int j0 = fb + 2 * jh, j1 = j0 + 1;
  float4 bsv = make_float4(bs[j0], bs[64 + j0], bs[j1], bs[64 + j1]);
  float4 bdv = make_float4(bd[j0], bd[64 + j0], bd[j1], bd[64 + j1]);
  int c0 = j0 >> 2, o = j0 & 3;
  int base = c0 * 8 + o;
#pragma unroll
  for (int r = 0; r < 2; ++r) {
    int rr = row0 + r0 + r;
    if (rr < n) {
      float4 a = r ? as1 : as0;
      float4 d = r ? ad1 : ad0;
      half2v s_h0 = {(_Float16)(a.x + bsv.x), (_Float16)(a.z + bsv.z)};
      half2v s_h1 = {(_Float16)(a.y + bsv.y), (_Float16)(a.w + bsv.w)};
      half2v d_h0 = {(_Float16)(d.x + bdv.x), (_Float16)(d.z + bdv.z)};
      half2v d_h1 = {(_Float16)(d.y + bdv.y), (_Float16)(d.w + bdv.w)};
      *(half2v*)&fs16[(size_t)rr * 128 + base] = s_h0;
      *(half2v*)&fs16[(size_t)rr * 128 + base + 4] = s_h1;
      *(half2v*)&fd16[(size_t)rr * 128 + base] = d_h0;
      *(half2v*)&fd16[(size_t)rr * 128 + base + 4] = d_h1;
    }
  }
}

// Persistent strided waves: wave w handles nodes w, w+nw, ... with the next
// node's metadata (row_start pair, fd row) prefetched before the edge loop.
__global__ __launch_bounds__(256) void gat_node_kernel(
    const _Float16* __restrict__ fs16, const _Float16* __restrict__ fd16,
    const float* __restrict__ attn, const int* __restrict__ row_start,
    const int* __restrict__ nbr, float* __restrict__ out, int n, int nw) {
  int gwid = (int)((blockIdx.x * 256 + threadIdx.x) >> 6);
  int lane = threadIdx.x & 63;
  int lp = lane & 15;
  int slot = lane >> 4;
  if (gwid >= n) return;

  half2v a0lo = {(_Float16)(attn[4 * lp] * RLN2),
                 (_Float16)(attn[4 * lp + 1] * RLN2)};
  half2v a0hi = {(_Float16)(attn[4 * lp + 2] * RLN2),
                 (_Float16)(attn[4 * lp + 3] * RLN2)};
  half2v a1lo = {(_Float16)(attn[64 + 4 * lp] * RLN2),
                 (_Float16)(attn[64 + 4 * lp + 1] * RLN2)};
  half2v a1hi = {(_Float16)(attn[64 + 4 * lp + 2] * RLN2),
                 (_Float16)(attn[64 + 4 * lp + 3] * RLN2)};
  const half8v c02 = {(_Float16)0.2f, (_Float16)0.2f, (_Float16)0.2f,
                      (_Float16)0.2f, (_Float16)0.2f, (_Float16)0.2f,
                      (_Float16)0.2f, (_Float16)0.2f};

  const half8v* fsC = (const half8v*)fs16;
  const half8v* fdC = (const half8v*)fd16;

#define EDGE_COMPUTE(xv, kill_cond)                                        \
  {                                                                        \
    half8v t = (xv) + fdh;                                                 \
    half8v m = __builtin_elementwise_max(t, t * c02);                      \
    float p0 = dot2(__builtin_shufflevector(m, m, 0, 1), a0lo, 0.f);       \
    p0 = dot2(__builtin_shufflevector(m, m, 2, 3), a0hi, p0);              \
    float p1 = dot2(__builtin_shufflevector(m, m, 4, 5), a1lo, 0.f);       \
    p1 = dot2(__builtin_shufflevector(m, m, 6, 7), a1hi, p1);              \
    p0 = dpp_add<0xB1>(p0);  p1 = dpp_add<0xB1>(p1);                       \
    p0 = dpp_add<0x4E>(p0);  p1 = dpp_add<0x4E>(p1);                       \
    p0 = dpp_add<0x141>(p0); p1 = dpp_add<0x141>(p1);                      \
    p0 = dpp_add<0x140>(p0); p1 = dpp_add<0x140>(p1);                      \
    float w0 = __builtin_amdgcn_exp2f(p0);                                 \
    float w1 = __builtin_amdgcn_exp2f(p1);                                 \
    if (kill_cond) { w0 = 0.f; w1 = 0.f; }                                 \
    d0 += w0; d1 += w1;                                                    \
    acc0.x = fmaf(w0, (float)(xv)[0], acc0.x);                             \
    acc0.y = fmaf(w0, (float)(xv)[1], acc0.y);                             \
    acc0.z = fmaf(w0, (float)(xv)[2], acc0.z);                             \
    acc0.w = fmaf(w0, (float)(xv)[3], acc0.w);                             \
    acc1.x = fmaf(w1, (float)(xv)[4], acc1.x);                             \
    acc1.y = fmaf(w1, (float)(xv)[5], acc1.y);                             \
    acc1.z = fmaf(w1, (float)(xv)[6], acc1.z);                             \
    acc1.w = fmaf(w1, (float)(xv)[7], acc1.w);                             \
  }

  int v = gwid;
  int e0 = row_start[v], e1 = row_start[v + 1];
  half8v fdh = fdC[(size_t)v * 16 + lp];

  while (true) {
    // prefetch next node's metadata so its latency hides under this node
    int vn = v + nw;
    int e0n = 0, e1n = 0;
    half8v fdhn = fdh;
    if (vn < n) {
      e0n = row_start[vn];
      e1n = row_start[vn + 1];
      fdhn = fdC[(size_t)vn * 16 + lp];
    }

    float4 acc0 = make_float4(0, 0, 0, 0), acc1 = make_float4(0, 0, 0, 0);
    float d0 = 0.f, d1 = 0.f;

    // self-loop edge, counted once via slot 0
    {
      half8v xs = fsC[(size_t)v * 16 + lp];
      EDGE_COMPUTE(xs, (slot != 0));
    }

    if (e0 < e1) {
      int last = e1 - 1;
      int u0 = nbr[min(e0 + slot, last)];
      int u1 = nbr[min(e0 + 4 + slot, last)];
      int u2 = nbr[min(e0 + 8 + slot, last)];
      half8v x0 = fsC[(size_t)u0 * 16 + lp];
      half8v x1 = fsC[(size_t)u1 * 16 + lp];
      half8v x2 = fsC[(size_t)u2 * 16 + lp];

      int i = e0;
      for (; i + 8 <= e1; i += 8) {
        int ua = nbr[min(i + 12 + slot, last)];
        int ub = nbr[min(i + 16 + slot, last)];
        half8v xa = fsC[(size_t)ua * 16 + lp];
        EDGE_COMPUTE(x0, (i + slot >= e1));
        half8v xb = fsC[(size_t)ub * 16 + lp];
        EDGE_COMPUTE(x1, (i + 4 + slot >= e1));
        x0 = x2; x1 = xa; x2 = xb;
      }
      if (i < e1) {
        EDGE_COMPUTE(x0, (i + slot >= e1));
        i += 4;
        if (i < e1) EDGE_COMPUTE(x1, (i + slot >= e1));
      }
    }

    // combine the 4 edge-slot groups: xor16 (swizzle) then xor32 (shfl)
    acc0.x = xor16_add(acc0.x); acc0.y = xor16_add(acc0.y);
    acc0.z = xor16_add(acc0.z); acc0.w = xor16_add(acc0.w);
    acc1.x = xor16_add(acc1.x); acc1.y = xor16_add(acc1.y);
    acc1.z = xor16_add(acc1.z); acc1.w = xor16_add(acc1.w);
    d0 = xor16_add(d0); d1 = xor16_add(d1);
    acc0.x += __shfl_xor(acc0.x, 32, 64); acc0.y += __shfl_xor(acc0.y, 32, 64);
    acc0.z += __shfl_xor(acc0.z, 32, 64); acc0.w += __shfl_xor(acc0.w, 32, 64);
    acc1.x += __shfl_xor(acc1.x, 32, 64); acc1.y += __shfl_xor(acc1.y, 32, 64);
    acc1.z += __shfl_xor(acc1.z, 32, 64); acc1.w += __shfl_xor(acc1.w, 32, 64);
    d0 += __shfl_xor(d0, 32, 64); d1 += __shfl_xor(d1, 32, 64);

    if (lane < 16) {
      float rd0 = 1.0f / d0, rd1 = 1.0f / d1;
      float4 o;
      o.x = 0.5f * (acc0.x * rd0 + acc1.x * rd1);
      o.y = 0.5f * (acc0.y * rd0 + acc1.y * rd1);
      o.z = 0.5f * (acc0.z * rd0 + acc1.z * rd1);
      o.w = 0.5f * (acc0.w * rd0 + acc1.w * rd1);
      ((float4*)out)[(size_t)v * 16 + lp] = o;
    }

    if (vn >= n) break;
    v = vn; e0 = e0n; e1 = e1n; fdh = fdhn;
  }
#undef EDGE_COMPUTE
}

extern "C" void kernel_launch(void* const* d_in, const int* in_sizes, int n_in,
                              void* d_out, int out_size, void* d_ws, size_t ws_size,
                              hipStream_t stream) {
  const float* h    = (const float*)d_in[0];
  const float* Wsrc = (const float*)d_in[1];
  const float* bsrc = (const float*)d_in[2];
  const float* Wdst = (const float*)d_in[3];
  const float* bdst = (const float*)d_in[4];
  const float* attn = (const float*)d_in[5];
  const int*   src  = (const int*)d_in[6];
  const int*   dst  = (const int*)d_in[7];
  int E = in_sizes[6];
  int N = in_sizes[0] / 64;
  int EM = E - N;                 // main block (no self-loops), sorted by src
  float* out = (float*)d_out;

  // workspace layout
  _Float16* fs16      = (_Float16*)d_ws;                      // N*128 fp16
  _Float16* fd16      = fs16 + (size_t)N * 128;               // N*128 fp16
  int*      row_start = (int*)(fd16 + (size_t)N * 128);       // N+1

  rowstart_kernel<<<(N + 256) / 256, 256, 0, stream>>>(src, row_start, EM, N);

  int pb = ((N + 63) / 64) * 2;
  int gb = 2048;                  // persistent: 8 blocks/CU, 8192 waves
  int nw = gb * 4;
  for (int l = 0; l < 2; ++l) {
    const float* hin = (l == 0) ? h : out;   // layer-1 output parked in d_out
    proj2_kernel<<<pb, 512, 0, stream>>>(hin, Wsrc + (size_t)l * 64 * 128,
                                         bsrc + (size_t)l * 128,
                                         Wdst + (size_t)l * 64 * 128,
                                         bdst + (size_t)l * 128, fs16, fd16, N);
    gat_node_kernel<<<gb, 256, 0, stream>>>(fs16, fd16, attn + (size_t)l * 128,
                                            row_start, dst, out, N, nw);
  }
}

// Round 11
// 153.006 us; speedup vs baseline: 1.1239x; 1.1239x over previous
//
#include <hip/hip_runtime.h>

// GATv2, 2 layers, F=64, H=2.
// Edge list (np.unique) is sorted by (src,dst), symmetric; self-loops are the
// last N entries. in-neighbors(v) = dst[src-run of v] + self loop.
//
// fs16/fd16 fp16, per-node CHUNK layout: 16 chunks x 16B, chunk c =
//   (h0 f[4c..4c+3] | h1 f[4c..4c+3]) -> one dwordx4 per edge per lane.
// gat: one wave per node (12500 blocks -> max TLP; persistent variant was
//      SLOWER, R10); 16 f-lanes x 4 edge-slots; self-edge folded into the
//      virtual edge stream (vi==0) -> one fewer batch per node; packed fp16
//      + dot2 logits; 4-DPP reduce; depth-3 gather pipeline.

#define RLN2 1.4426950408889634f

typedef _Float16 half8v __attribute__((ext_vector_type(8)));
typedef _Float16 half2v __attribute__((ext_vector_type(2)));

template <int CTRL>
__device__ __forceinline__ float dpp_add(float x) {
  return x + __int_as_float(__builtin_amdgcn_update_dpp(
                 0, __float_as_int(x), CTRL, 0xF, 0xF, true));
}

__device__ __forceinline__ float xor16_add(float x) {
  return x + __int_as_float(
                 __builtin_amdgcn_ds_swizzle(__float_as_int(x), 0x401F));
}

__device__ __forceinline__ float dot2(half2v a, half2v b, float c) {
#if __has_builtin(__builtin_amdgcn_fdot2)
  return __builtin_amdgcn_fdot2(a, b, c, false);
#else
  return fmaf((float)a.x, (float)b.x, fmaf((float)a.y, (float)b.y, c));
#endif
}

// row_start[v] = lower_bound(src[0..EM), v); row_start[n] = EM.
__global__ void rowstart_kernel(const int* __restrict__ src,
                                int* __restrict__ row_start, int EM, int n) {
  int v = blockIdx.x * blockDim.x + threadIdx.x;
  if (v > n) return;
  if (v == n) { row_start[n] = EM; return; }
  int lo = 0, hi = EM;
  while (lo < hi) {
    int mid = (lo + hi) >> 1;
    if (src[mid] < v) lo = mid + 1; else hi = mid;
  }
  row_start[v] = lo;
}

// Fused projection: block = (64-row tile) x (32-col half).
// LDS: WsL[4096] | WdL[4096] packed quads, hL[64][68] padded.
// 512 threads: jh = tid&15, rg = tid>>4 (2 rows each).
// Outputs fp16 chunk layout: buf[n*128 + (f>>2)*8 + head*4 + (f&3)].
__global__ __launch_bounds__(512) void proj2_kernel(
    const float* __restrict__ hin, const float* __restrict__ Ws,
    const float* __restrict__ bs, const float* __restrict__ Wd,
    const float* __restrict__ bd, _Float16* __restrict__ fs16,
    _Float16* __restrict__ fd16, int n) {
  __shared__ float lds[12544];
  int tid = threadIdx.x;
  int tile = blockIdx.x >> 1;
  int half = blockIdx.x & 1;
  int fb = half * 32;
  int row0 = tile * 64;

  const float4* Ws4 = (const float4*)Ws;
  const float4* Wd4 = (const float4*)Wd;
#pragma unroll
  for (int t = 0; t < 2; ++t) {
    int g = tid + t * 512;
    int k = g >> 4, part = (g >> 3) & 1, c4 = g & 7;
    int srcf4 = k * 32 + part * 16 + half * 8 + c4;
    float4 vs = Ws4[srcf4];
    float4 vd = Wd4[srcf4];
    int base = k * 64 + 8 * c4 + part;
    lds[base + 0] = vs.x; lds[base + 2] = vs.y;
    lds[base + 4] = vs.z; lds[base + 6] = vs.w;
    lds[4096 + base + 0] = vd.x; lds[4096 + base + 2] = vd.y;
    lds[4096 + base + 4] = vd.z; lds[4096 + base + 6] = vd.w;
  }
  const float4* h4 = (const float4*)hin;
#pragma unroll
  for (int t = 0; t < 2; ++t) {
    int idx = tid + t * 512;
    int r = idx >> 4, c = idx & 15;
    int rr = min(row0 + r, n - 1);
    *(float4*)&lds[8192 + r * 68 + c * 4] = h4[(size_t)rr * 16 + c];
  }
  __syncthreads();

  const float* WsL = lds;
  const float* WdL = lds + 4096;
  const float* hL = lds + 8192;

  int jh = tid & 15;
  int rg = tid >> 4;
  int r0 = rg * 2;

  float4 as0 = make_float4(0, 0, 0, 0), as1 = make_float4(0, 0, 0, 0);
  float4 ad0 = make_float4(0, 0, 0, 0), ad1 = make_float4(0, 0, 0, 0);

#pragma unroll 4
  for (int k4 = 0; k4 < 16; ++k4) {
    float4 hv0 = *(const float4*)&hL[r0 * 68 + k4 * 4];
    float4 hv1 = *(const float4*)&hL[(r0 + 1) * 68 + k4 * 4];
    float h0a[4] = {hv0.x, hv0.y, hv0.z, hv0.w};
    float h1a[4] = {hv1.x, hv1.y, hv1.z, hv1.w};
#pragma unroll
    for (int kk = 0; kk < 4; ++kk) {
      int k = k4 * 4 + kk;
      float4 ws = *(const float4*)&WsL[k * 64 + jh * 4];
      float4 wd = *(const float4*)&WdL[k * 64 + jh * 4];
      as0.x = fmaf(h0a[kk], ws.x, as0.x); as0.y = fmaf(h0a[kk], ws.y, as0.y);
      as0.z = fmaf(h0a[kk], ws.z, as0.z); as0.w = fmaf(h0a[kk], ws.w, as0.w);
      as1.x = fmaf(h1a[kk], ws.x, as1.x); as1.y = fmaf(h1a[kk], ws.y, as1.y);
      as1.z = fmaf(h1a[kk], ws.z, as1.z); as1.w = fmaf(h1a[kk], ws.w, as1.w);
      ad0.x = fmaf(h0a[kk], wd.x, ad0.x); ad0.y = fmaf(h0a[kk], wd.y, ad0.y);
      ad0.z = fmaf(h0a[kk], wd.z, ad0.z); ad0.w = fmaf(h0a[kk], wd.w, ad0.w);
      ad1.x = fmaf(h1a[kk], wd.x, ad1.x); ad1.y = fmaf(h1a[kk], wd.y, ad1.y);
      ad1.z = fmaf(h1a[kk], wd.z, ad1.z); ad1.w = fmaf(h1a[kk], wd.w, ad1.w);
    }
  }

  int j0 = fb + 2 * jh, j1 = j0 + 1;
  float4 bsv = make_float4(bs[j0], bs[64 + j0], bs[j1], bs[64 + j1]);
  float4 bdv = make_float4(bd[j0], bd[64 + j0], bd[j1], bd[64 + j1]);
  int c0 = j0 >> 2, o = j0 & 3;
  int base = c0 * 8 + o;
#pragma unroll
  for (int r = 0; r < 2; ++r) {
    int rr = row0 + r0 + r;
    if (rr < n) {
      float4 a = r ? as1 : as0;
      float4 d = r ? ad1 : ad0;
      half2v s_h0 = {(_Float16)(a.x + bsv.x), (_Float16)(a.z + bsv.z)};
      half2v s_h1 = {(_Float16)(a.y + bsv.y), (_Float16)(a.w + bsv.w)};
      half2v d_h0 = {(_Float16)(d.x + bdv.x), (_Float16)(d.z + bdv.z)};
      half2v d_h1 = {(_Float16)(d.y + bdv.y), (_Float16)(d.w + bdv.w)};
      *(half2v*)&fs16[(size_t)rr * 128 + base] = s_h0;
      *(half2v*)&fs16[(size_t)rr * 128 + base + 4] = s_h1;
      *(half2v*)&fd16[(size_t)rr * 128 + base] = d_h0;
      *(half2v*)&fd16[(size_t)rr * 128 + base + 4] = d_h1;
    }
  }
}

// One wave per dst node; virtual edge stream = [self, nbr[e0..e1)].
__global__ __launch_bounds__(256) void gat_node_kernel(
    const _Float16* __restrict__ fs16, const _Float16* __restrict__ fd16,
    const float* __restrict__ attn, const int* __restrict__ row_start,
    const int* __restrict__ nbr, float* __restrict__ out, int n) {
  int wid = (int)((blockIdx.x * 256 + threadIdx.x) >> 6);
  int lane = threadIdx.x & 63;
  if (wid >= n) return;
  int lp = lane & 15;    // f-lane: chunk lp = h0 f[4lp..4lp+3] | h1 same
  int slot = lane >> 4;  // edge slot 0..3

  half2v a0lo = {(_Float16)(attn[4 * lp] * RLN2),
                 (_Float16)(attn[4 * lp + 1] * RLN2)};
  half2v a0hi = {(_Float16)(attn[4 * lp + 2] * RLN2),
                 (_Float16)(attn[4 * lp + 3] * RLN2)};
  half2v a1lo = {(_Float16)(attn[64 + 4 * lp] * RLN2),
                 (_Float16)(attn[64 + 4 * lp + 1] * RLN2)};
  half2v a1hi = {(_Float16)(attn[64 + 4 * lp + 2] * RLN2),
                 (_Float16)(attn[64 + 4 * lp + 3] * RLN2)};
  const half8v c02 = {(_Float16)0.2f, (_Float16)0.2f, (_Float16)0.2f,
                      (_Float16)0.2f, (_Float16)0.2f, (_Float16)0.2f,
                      (_Float16)0.2f, (_Float16)0.2f};

  const half8v* fsC = (const half8v*)fs16;
  const half8v* fdC = (const half8v*)fd16;
  half8v fdh = fdC[(size_t)wid * 16 + lp];

  float4 acc0 = make_float4(0, 0, 0, 0), acc1 = make_float4(0, 0, 0, 0);
  float d0 = 0.f, d1 = 0.f;

#define EDGE_COMPUTE(xv, kill_cond)                                        \
  {                                                                        \
    half8v t = (xv) + fdh;                                                 \
    half8v m = __builtin_elementwise_max(t, t * c02);                      \
    float p0 = dot2(__builtin_shufflevector(m, m, 0, 1), a0lo, 0.f);       \
    p0 = dot2(__builtin_shufflevector(m, m, 2, 3), a0hi, p0);              \
    float p1 = dot2(__builtin_shufflevector(m, m, 4, 5), a1lo, 0.f);       \
    p1 = dot2(__builtin_shufflevector(m, m, 6, 7), a1hi, p1);              \
    p0 = dpp_add<0xB1>(p0);  p1 = dpp_add<0xB1>(p1);                       \
    p0 = dpp_add<0x4E>(p0);  p1 = dpp_add<0x4E>(p1);                       \
    p0 = dpp_add<0x141>(p0); p1 = dpp_add<0x141>(p1);                      \
    p0 = dpp_add<0x140>(p0); p1 = dpp_add<0x140>(p1);                      \
    float w0 = __builtin_amdgcn_exp2f(p0);                                 \
    float w1 = __builtin_amdgcn_exp2f(p1);                                 \
    if (kill_cond) { w0 = 0.f; w1 = 0.f; }                                 \
    d0 += w0; d1 += w1;                                                    \
    acc0.x = fmaf(w0, (float)(xv)[0], acc0.x);                             \
    acc0.y = fmaf(w0, (float)(xv)[1], acc0.y);                             \
    acc0.z = fmaf(w0, (float)(xv)[2], acc0.z);                             \
    acc0.w = fmaf(w0, (float)(xv)[3], acc0.w);                             \
    acc1.x = fmaf(w1, (float)(xv)[4], acc1.x);                             \
    acc1.y = fmaf(w1, (float)(xv)[5], acc1.y);                             \
    acc1.z = fmaf(w1, (float)(xv)[6], acc1.z);                             \
    acc1.w = fmaf(w1, (float)(xv)[7], acc1.w);                             \
  }

  int e0 = row_start[wid], e1 = row_start[wid + 1];
  int deg = e1 - e0;
  int vt = deg + 1;                       // virtual edges incl self at vi==0
  int lastc = (deg > 0) ? (deg - 1) : 0;  // clamp for nbr offset

  // depth-3 pipeline over virtual batches (4 slots each)
  int u0 = (slot == 0) ? wid : nbr[e0 + min(slot - 1, lastc)];
  int u1 = nbr[e0 + min(3 + slot, lastc)];
  int u2 = nbr[e0 + min(7 + slot, lastc)];
  half8v x0 = fsC[(size_t)u0 * 16 + lp];
  half8v x1 = fsC[(size_t)u1 * 16 + lp];
  half8v x2 = fsC[(size_t)u2 * 16 + lp];

  int i = 0;
  for (; i + 8 <= vt; i += 8) {
    int ua = nbr[e0 + min(i + 11 + slot, lastc)];
    int ub = nbr[e0 + min(i + 15 + slot, lastc)];
    half8v xa = fsC[(size_t)ua * 16 + lp];
    EDGE_COMPUTE(x0, false);                 // vi = i+slot   < vt guaranteed
    half8v xb = fsC[(size_t)ub * 16 + lp];
    EDGE_COMPUTE(x1, false);                 // vi = i+4+slot < vt guaranteed
    x0 = x2; x1 = xa; x2 = xb;
  }
  if (i < vt) {
    EDGE_COMPUTE(x0, (i + slot >= vt));
    i += 4;
    if (i < vt) EDGE_COMPUTE(x1, (i + slot >= vt));
  }

  // combine the 4 edge-slot groups: xor16 (swizzle) then xor32 (shfl)
  acc0.x = xor16_add(acc0.x); acc0.y = xor16_add(acc0.y);
  acc0.z = xor16_add(acc0.z); acc0.w = xor16_add(acc0.w);
  acc1.x = xor16_add(acc1.x); acc1.y = xor16_add(acc1.y);
  acc1.z = xor16_add(acc1.z); acc1.w = xor16_add(acc1.w);
  d0 = xor16_add(d0); d1 = xor16_add(d1);
  acc0.x += __shfl_xor(acc0.x, 32, 64); acc0.y += __shfl_xor(acc0.y, 32, 64);
  acc0.z += __shfl_xor(acc0.z, 32, 64); acc0.w += __shfl_xor(acc0.w, 32, 64);
  acc1.x += __shfl_xor(acc1.x, 32, 64); acc1.y += __shfl_xor(acc1.y, 32, 64);
  acc1.z += __shfl_xor(acc1.z, 32, 64); acc1.w += __shfl_xor(acc1.w, 32, 64);
  d0 += __shfl_xor(d0, 32, 64); d1 += __shfl_xor(d1, 32, 64);

  if (lane < 16) {
    float rd0 = 1.0f / d0, rd1 = 1.0f / d1;
    float4 o;
    o.x = 0.5f * (acc0.x * rd0 + acc1.x * rd1);
    o.y = 0.5f * (acc0.y * rd0 + acc1.y * rd1);
    o.z = 0.5f * (acc0.z * rd0 + acc1.z * rd1);
    o.w = 0.5f * (acc0.w * rd0 + acc1.w * rd1);
    ((float4*)out)[(size_t)wid * 16 + lp] = o;   // feats 4lp..4lp+3
  }
#undef EDGE_COMPUTE
}

extern "C" void kernel_launch(void* const* d_in, const int* in_sizes, int n_in,
                              void* d_out, int out_size, void* d_ws, size_t ws_size,
                              hipStream_t stream) {
  const float* h    = (const float*)d_in[0];
  const float* Wsrc = (const float*)d_in[1];
  const float* bsrc = (const float*)d_in[2];
  const float* Wdst = (const float*)d_in[3];
  const float* bdst = (const float*)d_in[4];
  const float* attn = (const float*)d_in[5];
  const int*   src  = (const int*)d_in[6];
  const int*   dst  = (const int*)d_in[7];
  int E = in_sizes[6];
  int N = in_sizes[0] / 64;
  int EM = E - N;                 // main block (no self-loops), sorted by src
  float* out = (float*)d_out;

  // workspace layout
  _Float16* fs16      = (_Float16*)d_ws;                      // N*128 fp16
  _Float16* fd16      = fs16 + (size_t)N * 128;               // N*128 fp16
  int*      row_start = (int*)(fd16 + (size_t)N * 128);       // N+1

  rowstart_kernel<<<(N + 256) / 256, 256, 0, stream>>>(src, row_start, EM, N);

  int pb = ((N + 63) / 64) * 2;
  int nb = (N + 3) / 4;
  for (int l = 0; l < 2; ++l) {
    const float* hin = (l == 0) ? h : out;   // layer-1 output parked in d_out
    proj2_kernel<<<pb, 512, 0, stream>>>(hin, Wsrc + (size_t)l * 64 * 128,
                                         bsrc + (size_t)l * 128,
                                         Wdst + (size_t)l * 64 * 128,
                                         bdst + (size_t)l * 128, fs16, fd16, N);
    gat_node_kernel<<<nb, 256, 0, stream>>>(fs16, fd16, attn + (size_t)l * 128,
                                            row_start, dst, out, N);
  }
}

// Round 12
// 152.336 us; speedup vs baseline: 1.1289x; 1.0044x over previous
//
#include <hip/hip_runtime.h>

// GATv2, 2 layers, F=64, H=2.
// Edge list (np.unique) is sorted by (src,dst), symmetric; self-loops are the
// last N entries. in-neighbors(v) = dst[src-run of v] + self loop.
//
// fs16/fd16 fp16, per-node CHUNK layout: 16 chunks x 16B, chunk c =
//   (h0 f[4c..4c+3] | h1 f[4c..4c+3]) -> one dwordx4 per edge per lane.
// gat: one wave per node, 128-thread blocks (2 waves) for fine-grain
//      retirement/backfill (256-thr was ~60% occ; persistent was slower,
//      R10); 16 f-lanes x 4 edge-slots; self-edge folded at vi==0; packed
//      fp16 + dot2 logits; 4-DPP reduce; depth-4 gather pipeline.

#define RLN2 1.4426950408889634f

typedef _Float16 half8v __attribute__((ext_vector_type(8)));
typedef _Float16 half2v __attribute__((ext_vector_type(2)));

template <int CTRL>
__device__ __forceinline__ float dpp_add(float x) {
  return x + __int_as_float(__builtin_amdgcn_update_dpp(
                 0, __float_as_int(x), CTRL, 0xF, 0xF, true));
}

__device__ __forceinline__ float xor16_add(float x) {
  return x + __int_as_float(
                 __builtin_amdgcn_ds_swizzle(__float_as_int(x), 0x401F));
}

__device__ __forceinline__ float dot2(half2v a, half2v b, float c) {
#if __has_builtin(__builtin_amdgcn_fdot2)
  return __builtin_amdgcn_fdot2(a, b, c, false);
#else
  return fmaf((float)a.x, (float)b.x, fmaf((float)a.y, (float)b.y, c));
#endif
}

// row_start[v] = lower_bound(src[0..EM), v); row_start[n] = EM.
__global__ void rowstart_kernel(const int* __restrict__ src,
                                int* __restrict__ row_start, int EM, int n) {
  int v = blockIdx.x * blockDim.x + threadIdx.x;
  if (v > n) return;
  if (v == n) { row_start[n] = EM; return; }
  int lo = 0, hi = EM;
  while (lo < hi) {
    int mid = (lo + hi) >> 1;
    if (src[mid] < v) lo = mid + 1; else hi = mid;
  }
  row_start[v] = lo;
}

// Fused projection: block = (64-row tile) x (32-col half).
// LDS: WsL[4096] | WdL[4096] packed quads, hL[64][68] padded.
// 512 threads: jh = tid&15, rg = tid>>4 (2 rows each).
// Outputs fp16 chunk layout: buf[n*128 + (f>>2)*8 + head*4 + (f&3)].
__global__ __launch_bounds__(512) void proj2_kernel(
    const float* __restrict__ hin, const float* __restrict__ Ws,
    const float* __restrict__ bs, const float* __restrict__ Wd,
    const float* __restrict__ bd, _Float16* __restrict__ fs16,
    _Float16* __restrict__ fd16, int n) {
  __shared__ float lds[12544];
  int tid = threadIdx.x;
  int tile = blockIdx.x >> 1;
  int half = blockIdx.x & 1;
  int fb = half * 32;
  int row0 = tile * 64;

  const float4* Ws4 = (const float4*)Ws;
  const float4* Wd4 = (const float4*)Wd;
#pragma unroll
  for (int t = 0; t < 2; ++t) {
    int g = tid + t * 512;
    int k = g >> 4, part = (g >> 3) & 1, c4 = g & 7;
    int srcf4 = k * 32 + part * 16 + half * 8 + c4;
    float4 vs = Ws4[srcf4];
    float4 vd = Wd4[srcf4];
    int base = k * 64 + 8 * c4 + part;
    lds[base + 0] = vs.x; lds[base + 2] = vs.y;
    lds[base + 4] = vs.z; lds[base + 6] = vs.w;
    lds[4096 + base + 0] = vd.x; lds[4096 + base + 2] = vd.y;
    lds[4096 + base + 4] = vd.z; lds[4096 + base + 6] = vd.w;
  }
  const float4* h4 = (const float4*)hin;
#pragma unroll
  for (int t = 0; t < 2; ++t) {
    int idx = tid + t * 512;
    int r = idx >> 4, c = idx & 15;
    int rr = min(row0 + r, n - 1);
    *(float4*)&lds[8192 + r * 68 + c * 4] = h4[(size_t)rr * 16 + c];
  }
  __syncthreads();

  const float* WsL = lds;
  const float* WdL = lds + 4096;
  const float* hL = lds + 8192;

  int jh = tid & 15;
  int rg = tid >> 4;
  int r0 = rg * 2;

  float4 as0 = make_float4(0, 0, 0, 0), as1 = make_float4(0, 0, 0, 0);
  float4 ad0 = make_float4(0, 0, 0, 0), ad1 = make_float4(0, 0, 0, 0);

#pragma unroll 4
  for (int k4 = 0; k4 < 16; ++k4) {
    float4 hv0 = *(const float4*)&hL[r0 * 68 + k4 * 4];
    float4 hv1 = *(const float4*)&hL[(r0 + 1) * 68 + k4 * 4];
    float h0a[4] = {hv0.x, hv0.y, hv0.z, hv0.w};
    float h1a[4] = {hv1.x, hv1.y, hv1.z, hv1.w};
#pragma unroll
    for (int kk = 0; kk < 4; ++kk) {
      int k = k4 * 4 + kk;
      float4 ws = *(const float4*)&WsL[k * 64 + jh * 4];
      float4 wd = *(const float4*)&WdL[k * 64 + jh * 4];
      as0.x = fmaf(h0a[kk], ws.x, as0.x); as0.y = fmaf(h0a[kk], ws.y, as0.y);
      as0.z = fmaf(h0a[kk], ws.z, as0.z); as0.w = fmaf(h0a[kk], ws.w, as0.w);
      as1.x = fmaf(h1a[kk], ws.x, as1.x); as1.y = fmaf(h1a[kk], ws.y, as1.y);
      as1.z = fmaf(h1a[kk], ws.z, as1.z); as1.w = fmaf(h1a[kk], ws.w, as1.w);
      ad0.x = fmaf(h0a[kk], wd.x, ad0.x); ad0.y = fmaf(h0a[kk], wd.y, ad0.y);
      ad0.z = fmaf(h0a[kk], wd.z, ad0.z); ad0.w = fmaf(h0a[kk], wd.w, ad0.w);
      ad1.x = fmaf(h1a[kk], wd.x, ad1.x); ad1.y = fmaf(h1a[kk], wd.y, ad1.y);
      ad1.z = fmaf(h1a[kk], wd.z, ad1.z); ad1.w = fmaf(h1a[kk], wd.w, ad1.w);
    }
  }

  int j0 = fb + 2 * jh, j1 = j0 + 1;
  float4 bsv = make_float4(bs[j0], bs[64 + j0], bs[j1], bs[64 + j1]);
  float4 bdv = make_float4(bd[j0], bd[64 + j0], bd[j1], bd[64 + j1]);
  int c0 = j0 >> 2, o = j0 & 3;
  int base = c0 * 8 + o;
#pragma unroll
  for (int r = 0; r < 2; ++r) {
    int rr = row0 + r0 + r;
    if (rr < n) {
      float4 a = r ? as1 : as0;
      float4 d = r ? ad1 : ad0;
      half2v s_h0 = {(_Float16)(a.x + bsv.x), (_Float16)(a.z + bsv.z)};
      half2v s_h1 = {(_Float16)(a.y + bsv.y), (_Float16)(a.w + bsv.w)};
      half2v d_h0 = {(_Float16)(d.x + bdv.x), (_Float16)(d.z + bdv.z)};
      half2v d_h1 = {(_Float16)(d.y + bdv.y), (_Float16)(d.w + bdv.w)};
      *(half2v*)&fs16[(size_t)rr * 128 + base] = s_h0;
      *(half2v*)&fs16[(size_t)rr * 128 + base + 4] = s_h1;
      *(half2v*)&fd16[(size_t)rr * 128 + base] = d_h0;
      *(half2v*)&fd16[(size_t)rr * 128 + base + 4] = d_h1;
    }
  }
}

// One wave per dst node; virtual edge stream = [self, nbr[e0..e1)].
// 128-thread blocks (2 waves) -> finer resource retirement, higher occupancy.
__global__ __launch_bounds__(128) void gat_node_kernel(
    const _Float16* __restrict__ fs16, const _Float16* __restrict__ fd16,
    const float* __restrict__ attn, const int* __restrict__ row_start,
    const int* __restrict__ nbr, float* __restrict__ out, int n) {
  int wid = (int)((blockIdx.x * 128 + threadIdx.x) >> 6);
  int lane = threadIdx.x & 63;
  if (wid >= n) return;
  int lp = lane & 15;    // f-lane: chunk lp = h0 f[4lp..4lp+3] | h1 same
  int slot = lane >> 4;  // edge slot 0..3

  half2v a0lo = {(_Float16)(attn[4 * lp] * RLN2),
                 (_Float16)(attn[4 * lp + 1] * RLN2)};
  half2v a0hi = {(_Float16)(attn[4 * lp + 2] * RLN2),
                 (_Float16)(attn[4 * lp + 3] * RLN2)};
  half2v a1lo = {(_Float16)(attn[64 + 4 * lp] * RLN2),
                 (_Float16)(attn[64 + 4 * lp + 1] * RLN2)};
  half2v a1hi = {(_Float16)(attn[64 + 4 * lp + 2] * RLN2),
                 (_Float16)(attn[64 + 4 * lp + 3] * RLN2)};
  const half8v c02 = {(_Float16)0.2f, (_Float16)0.2f, (_Float16)0.2f,
                      (_Float16)0.2f, (_Float16)0.2f, (_Float16)0.2f,
                      (_Float16)0.2f, (_Float16)0.2f};

  const half8v* fsC = (const half8v*)fs16;
  const half8v* fdC = (const half8v*)fd16;
  half8v fdh = fdC[(size_t)wid * 16 + lp];

  float4 acc0 = make_float4(0, 0, 0, 0), acc1 = make_float4(0, 0, 0, 0);
  float d0 = 0.f, d1 = 0.f;

#define EDGE_COMPUTE(xv, kill_cond)                                        \
  {                                                                        \
    half8v t = (xv) + fdh;                                                 \
    half8v m = __builtin_elementwise_max(t, t * c02);                      \
    float p0 = dot2(__builtin_shufflevector(m, m, 0, 1), a0lo, 0.f);       \
    p0 = dot2(__builtin_shufflevector(m, m, 2, 3), a0hi, p0);              \
    float p1 = dot2(__builtin_shufflevector(m, m, 4, 5), a1lo, 0.f);       \
    p1 = dot2(__builtin_shufflevector(m, m, 6, 7), a1hi, p1);              \
    p0 = dpp_add<0xB1>(p0);  p1 = dpp_add<0xB1>(p1);                       \
    p0 = dpp_add<0x4E>(p0);  p1 = dpp_add<0x4E>(p1);                       \
    p0 = dpp_add<0x141>(p0); p1 = dpp_add<0x141>(p1);                      \
    p0 = dpp_add<0x140>(p0); p1 = dpp_add<0x140>(p1);                      \
    float w0 = __builtin_amdgcn_exp2f(p0);                                 \
    float w1 = __builtin_amdgcn_exp2f(p1);                                 \
    if (kill_cond) { w0 = 0.f; w1 = 0.f; }                                 \
    d0 += w0; d1 += w1;                                                    \
    acc0.x = fmaf(w0, (float)(xv)[0], acc0.x);                             \
    acc0.y = fmaf(w0, (float)(xv)[1], acc0.y);                             \
    acc0.z = fmaf(w0, (float)(xv)[2], acc0.z);                             \
    acc0.w = fmaf(w0, (float)(xv)[3], acc0.w);                             \
    acc1.x = fmaf(w1, (float)(xv)[4], acc1.x);                             \
    acc1.y = fmaf(w1, (float)(xv)[5], acc1.y);                             \
    acc1.z = fmaf(w1, (float)(xv)[6], acc1.z);                             \
    acc1.w = fmaf(w1, (float)(xv)[7], acc1.w);                             \
  }

  int e0 = row_start[wid], e1 = row_start[wid + 1];
  int deg = e1 - e0;
  int vt = deg + 1;                       // virtual edges incl self at vi==0
  int lastc = (deg > 0) ? (deg - 1) : 0;  // clamp for nbr offset

  // depth-4 pipeline over virtual batches (4 slots each)
  int u0 = (slot == 0) ? wid : nbr[e0 + min(slot - 1, lastc)];
  int u1 = nbr[e0 + min(3 + slot, lastc)];
  int u2 = nbr[e0 + min(7 + slot, lastc)];
  int u3 = nbr[e0 + min(11 + slot, lastc)];
  half8v x0 = fsC[(size_t)u0 * 16 + lp];
  half8v x1 = fsC[(size_t)u1 * 16 + lp];
  half8v x2 = fsC[(size_t)u2 * 16 + lp];
  half8v x3 = fsC[(size_t)u3 * 16 + lp];

  int i = 0;
  for (; i + 8 <= vt; i += 8) {
    int ua = nbr[e0 + min(i + 15 + slot, lastc)];
    int ub = nbr[e0 + min(i + 19 + slot, lastc)];
    half8v xa = fsC[(size_t)ua * 16 + lp];
    EDGE_COMPUTE(x0, false);                 // vi = i+slot   < vt guaranteed
    half8v xb = fsC[(size_t)ub * 16 + lp];
    EDGE_COMPUTE(x1, false);                 // vi = i+4+slot < vt guaranteed
    x0 = x2; x1 = x3; x2 = xa; x3 = xb;
  }
  if (i < vt) {
    EDGE_COMPUTE(x0, (i + slot >= vt));
    i += 4;
    if (i < vt) EDGE_COMPUTE(x1, (i + slot >= vt));
  }

  // combine the 4 edge-slot groups: xor16 (swizzle) then xor32 (shfl)
  acc0.x = xor16_add(acc0.x); acc0.y = xor16_add(acc0.y);
  acc0.z = xor16_add(acc0.z); acc0.w = xor16_add(acc0.w);
  acc1.x = xor16_add(acc1.x); acc1.y = xor16_add(acc1.y);
  acc1.z = xor16_add(acc1.z); acc1.w = xor16_add(acc1.w);
  d0 = xor16_add(d0); d1 = xor16_add(d1);
  acc0.x += __shfl_xor(acc0.x, 32, 64); acc0.y += __shfl_xor(acc0.y, 32, 64);
  acc0.z += __shfl_xor(acc0.z, 32, 64); acc0.w += __shfl_xor(acc0.w, 32, 64);
  acc1.x += __shfl_xor(acc1.x, 32, 64); acc1.y += __shfl_xor(acc1.y, 32, 64);
  acc1.z += __shfl_xor(acc1.z, 32, 64); acc1.w += __shfl_xor(acc1.w, 32, 64);
  d0 += __shfl_xor(d0, 32, 64); d1 += __shfl_xor(d1, 32, 64);

  if (lane < 16) {
    float rd0 = 1.0f / d0, rd1 = 1.0f / d1;
    float4 o;
    o.x = 0.5f * (acc0.x * rd0 + acc1.x * rd1);
    o.y = 0.5f * (acc0.y * rd0 + acc1.y * rd1);
    o.z = 0.5f * (acc0.z * rd0 + acc1.z * rd1);
    o.w = 0.5f * (acc0.w * rd0 + acc1.w * rd1);
    ((float4*)out)[(size_t)wid * 16 + lp] = o;   // feats 4lp..4lp+3
  }
#undef EDGE_COMPUTE
}

extern "C" void kernel_launch(void* const* d_in, const int* in_sizes, int n_in,
                              void* d_out, int out_size, void* d_ws, size_t ws_size,
                              hipStream_t stream) {
  const float* h    = (const float*)d_in[0];
  const float* Wsrc = (const float*)d_in[1];
  const float* bsrc = (const float*)d_in[2];
  const float* Wdst = (const float*)d_in[3];
  const float* bdst = (const float*)d_in[4];
  const float* attn = (const float*)d_in[5];
  const int*   src  = (const int*)d_in[6];
  const int*   dst  = (const int*)d_in[7];
  int E = in_sizes[6];
  int N = in_sizes[0] / 64;
  int EM = E - N;                 // main block (no self-loops), sorted by src
  float* out = (float*)d_out;

  // workspace layout
  _Float16* fs16      = (_Float16*)d_ws;                      // N*128 fp16
  _Float16* fd16      = fs16 + (size_t)N * 128;               // N*128 fp16
  int*      row_start = (int*)(fd16 + (size_t)N * 128);       // N+1

  rowstart_kernel<<<(N + 256) / 256, 256, 0, stream>>>(src, row_start, EM, N);

  int pb = ((N + 63) / 64) * 2;
  int nb = (N + 1) / 2;           // 128-thread blocks, 2 nodes each
  for (int l = 0; l < 2; ++l) {
    const float* hin = (l == 0) ? h : out;   // layer-1 output parked in d_out
    proj2_kernel<<<pb, 512, 0, stream>>>(hin, Wsrc + (size_t)l * 64 * 128,
                                         bsrc + (size_t)l * 128,
                                         Wdst + (size_t)l * 64 * 128,
                                         bdst + (size_t)l * 128, fs16, fd16, N);
    gat_node_kernel<<<nb, 128, 0, stream>>>(fs16, fd16, attn + (size_t)l * 128,
                                            row_start, dst, out, N);
  }
}